// Round 5
// baseline (110.049 us; speedup 1.0000x reference)
//
#include <hip/hip_runtime.h>

// FusionLoss: B=256, K=16, HW=65536.
// Single fused kernel: one block per sample (256 blocks x 64 threads).
// Lanes 0..15 gather pred/target/mask in parallel, share via LDS,
// wave-reduce smooth-L1; lane 0 computes the 12-edge variance term and
// atomicAdds 3 partials into a 16 B accumulator in d_ws. The 256th block
// to finish reads the totals back (coherent atomic read) and writes the
// scalar loss. Accumulator zeroed via a 16 B hipMemsetAsync node.

#define B_   256
#define K_   16
#define HW_  65536

struct Acc {
    float    sl1;
    float    num;
    float    var;
    unsigned cnt;
};

__global__ __launch_bounds__(64, 8)
void fusion_fused(const float* __restrict__ output,
                  const int*   __restrict__ mask,
                  const int*   __restrict__ ind,
                  const float* __restrict__ target,
                  const float* __restrict__ gt2d,
                  Acc*         __restrict__ acc,
                  float*       __restrict__ out) {
    const int b    = blockIdx.x;
    const int lane = threadIdx.x;   // 0..63, single wave

    __shared__ float s_pred[K_];
    __shared__ float s_tgt[K_];
    __shared__ float s_xy[2 * K_];

    float psl1 = 0.0f, pnum = 0.0f;
    int   pm   = 0;

    if (lane < 2 * K_) s_xy[lane] = gt2d[b * 2 * K_ + lane];
    if (lane < K_) {
        const int   idx = ind[b * K_ + lane];
        const float p   = output[b * HW_ + idx];
        const float t   = target[b * K_ + lane];
        const int   mk  = mask[b * K_ + lane];
        s_pred[lane] = p;
        s_tgt[lane]  = t;
        pm = mk;
        if (mk) {
            const float ad = fabsf(p - t);
            psl1 = (ad < 1.0f) ? 0.5f * ad * ad : (ad - 0.5f);
            pnum = 1.0f;
        }
    }

    // 16-lane tree reduce (lanes 16..31 hold zeros)
    #pragma unroll
    for (int off = 8; off > 0; off >>= 1) {
        psl1 += __shfl_down(psl1, off);
        pnum += __shfl_down(pnum, off);
        pm   += __shfl_down(pm,   off);
    }

    __syncthreads();   // drain LDS writes (single wave: cheap)

    if (lane == 0) {
        const int   id1[12] = {0, 1, 3, 4, 10, 11, 13, 14, 2, 3, 12, 13};
        const int   id2[12] = {1, 2, 4, 5, 11, 12, 14, 15, 6, 6,  8,  8};
        const float wgt[12] = {1.0085885098415446f, 1.0f, 1.0f, 1.0085885098415446f,
                               1.1375361376887123f, 1.0f, 1.0f, 1.1375361376887123f,
                               1.0f, 1.0f, 1.0f, 1.0f};
        const int   gid[12] = {0, 0, 0, 0, 1, 1, 1, 1, 2, 2, 3, 3};

        float l[12];
        bool  vis[12];
        float num_g[4] = {0.f, 0.f, 0.f, 0.f};
        float sum_g[4] = {0.f, 0.f, 0.f, 0.f};
        #pragma unroll
        for (int e = 0; e < 12; ++e) {
            const int i1 = id1[e], i2 = id2[e];
            const float dx = s_xy[2 * i1]     - s_xy[2 * i2];
            const float dy = s_xy[2 * i1 + 1] - s_xy[2 * i2 + 1];
            const float dz = s_pred[i1] - s_pred[i2];
            const float le = sqrtf(dx * dx + dy * dy + dz * dz) * wgt[e];
            l[e] = le;
            const bool v = (s_tgt[i1] > 0.5f) && (s_tgt[i2] > 0.5f);
            vis[e] = v;
            if (v) {
                num_g[gid[e]] += 1.0f;
                sum_g[gid[e]] += le;
            }
        }

        float E[4], ng4[4];
        #pragma unroll
        for (int g = 0; g < 4; ++g) {
            const float n = num_g[g];
            ng4[g] = fmaxf(n, 1.0f);
            E[g]   = (n > 0.5f) ? (sum_g[g] / ng4[g]) : 0.0f;
        }

        float per = 0.0f;
        #pragma unroll
        for (int e = 0; e < 12; ++e) {
            if (vis[e] && (l[e] > 0.0f)) {
                const float d = l[e] - E[gid[e]];
                per += d * d / (2.0f * ng4[gid[e]]);
            }
        }
        const float var_c = (pm == 0) ? per : 0.0f;

        // ---- global accumulation; last block finalizes ----
        atomicAdd(&acc->sl1, psl1);
        atomicAdd(&acc->num, pnum);
        atomicAdd(&acc->var, var_c);
        __threadfence();
        const unsigned old = atomicAdd(&acc->cnt, 1u);
        if (old == (unsigned)(B_ - 1)) {
            // coherent read-back of the totals (atomic returns old value)
            const float tsl1 = atomicAdd(&acc->sl1, 0.0f);
            const float tnum = atomicAdd(&acc->num, 0.0f);
            const float tvar = atomicAdd(&acc->var, 0.0f);
            out[0] = tsl1 / (tnum + 0.0001f) + 0.01f * (tvar / (float)B_);
        }
    }
}

extern "C" void kernel_launch(void* const* d_in, const int* in_sizes, int n_in,
                              void* d_out, int out_size, void* d_ws, size_t ws_size,
                              hipStream_t stream) {
    const float* output = (const float*)d_in[0];  // (256,1,256,256) f32
    const int*   mask   = (const int*)  d_in[1];  // (256,16) i32
    const int*   ind    = (const int*)  d_in[2];  // (256,16) i32
    const float* target = (const float*)d_in[3];  // (256,16,1) f32
    const float* gt2d   = (const float*)d_in[4];  // (256,32) f32
    float* out = (float*)d_out;                   // scalar f32
    Acc*   acc = (Acc*)d_ws;                      // 16 B accumulator

    hipMemsetAsync(d_ws, 0, sizeof(Acc), stream);
    fusion_fused<<<B_, 64, 0, stream>>>(output, mask, ind, target, gt2d, acc, out);
}

// Round 9
// 95.560 us; speedup vs baseline: 1.1516x; 1.1516x over previous
//
#include <hip/hip_runtime.h>

// FusionLoss: B=256, K=16, HW=65536.  (R1 structure — best measured: 96 µs)
// Kernel 1: one block per sample (256 blocks x 64 threads). Lanes 0..15
//   gather pred/target/mask in parallel (the latency-bound part), share via
//   LDS, wave-reduce smooth-L1, lane 0 computes the 12-edge variance term
//   serially, writes one float4 partial per block.
// Kernel 2: one block of 256 threads reduces the 256 partials (L2-hot) and
//   writes the scalar loss. No atomics, no memset node.

#define B_   256
#define K_   16
#define HW_  65536

__global__ __launch_bounds__(64, 8)
void fusion_partial(const float* __restrict__ output,
                    const int*   __restrict__ mask,
                    const int*   __restrict__ ind,
                    const float* __restrict__ target,
                    const float* __restrict__ gt2d,
                    float4*      __restrict__ partial) {
    const int b    = blockIdx.x;
    const int lane = threadIdx.x;   // 0..63, single wave

    __shared__ float s_pred[K_];
    __shared__ float s_tgt[K_];
    __shared__ float s_xy[2 * K_];

    float psl1 = 0.0f, pnum = 0.0f;
    int   pm   = 0;

    if (lane < 2 * K_) s_xy[lane] = gt2d[b * 2 * K_ + lane];
    if (lane < K_) {
        const int   idx = ind[b * K_ + lane];
        const float p   = output[b * HW_ + idx];
        const float t   = target[b * K_ + lane];
        const int   mk  = mask[b * K_ + lane];
        s_pred[lane] = p;
        s_tgt[lane]  = t;
        pm = mk;
        if (mk) {
            const float ad = fabsf(p - t);
            psl1 = (ad < 1.0f) ? 0.5f * ad * ad : (ad - 0.5f);
            pnum = 1.0f;
        }
    }

    // 16-lane tree reduce (lanes 16..31 hold zeros)
    #pragma unroll
    for (int off = 8; off > 0; off >>= 1) {
        psl1 += __shfl_down(psl1, off);
        pnum += __shfl_down(pnum, off);
        pm   += __shfl_down(pm,   off);
    }

    __syncthreads();   // drain LDS writes (single wave: cheap)

    if (lane == 0) {
        const int   id1[12] = {0, 1, 3, 4, 10, 11, 13, 14, 2, 3, 12, 13};
        const int   id2[12] = {1, 2, 4, 5, 11, 12, 14, 15, 6, 6,  8,  8};
        const float wgt[12] = {1.0085885098415446f, 1.0f, 1.0f, 1.0085885098415446f,
                               1.1375361376887123f, 1.0f, 1.0f, 1.1375361376887123f,
                               1.0f, 1.0f, 1.0f, 1.0f};
        const int   gid[12] = {0, 0, 0, 0, 1, 1, 1, 1, 2, 2, 3, 3};

        float l[12];
        bool  vis[12];
        float num_g[4] = {0.f, 0.f, 0.f, 0.f};
        float sum_g[4] = {0.f, 0.f, 0.f, 0.f};
        #pragma unroll
        for (int e = 0; e < 12; ++e) {
            const int i1 = id1[e], i2 = id2[e];
            const float dx = s_xy[2 * i1]     - s_xy[2 * i2];
            const float dy = s_xy[2 * i1 + 1] - s_xy[2 * i2 + 1];
            const float dz = s_pred[i1] - s_pred[i2];
            const float le = sqrtf(dx * dx + dy * dy + dz * dz) * wgt[e];
            l[e] = le;
            const bool v = (s_tgt[i1] > 0.5f) && (s_tgt[i2] > 0.5f);
            vis[e] = v;
            if (v) {
                num_g[gid[e]] += 1.0f;
                sum_g[gid[e]] += le;
            }
        }

        float E[4], ng4[4];
        #pragma unroll
        for (int g = 0; g < 4; ++g) {
            const float n = num_g[g];
            ng4[g] = fmaxf(n, 1.0f);
            E[g]   = (n > 0.5f) ? (sum_g[g] / ng4[g]) : 0.0f;
        }

        float per = 0.0f;
        #pragma unroll
        for (int e = 0; e < 12; ++e) {
            if (vis[e] && (l[e] > 0.0f)) {
                const float d = l[e] - E[gid[e]];
                per += d * d / (2.0f * ng4[gid[e]]);
            }
        }
        const float var_c = (pm == 0) ? per : 0.0f;

        partial[b] = make_float4(psl1, pnum, var_c, 0.0f);
    }
}

__global__ __launch_bounds__(256, 1)
void fusion_final(const float4* __restrict__ partial,
                  float*        __restrict__ out) {
    const int t = threadIdx.x;   // 0..255, one per sample
    const float4 v = partial[t];
    float sl1 = v.x, num = v.y, var = v.z;

    #pragma unroll
    for (int off = 32; off > 0; off >>= 1) {
        sl1 += __shfl_down(sl1, off);
        num += __shfl_down(num, off);
        var += __shfl_down(var, off);
    }
    __shared__ float s_sl1[4], s_num[4], s_var[4];
    const int wave = t >> 6;
    const int lane = t & 63;
    if (lane == 0) {
        s_sl1[wave] = sl1;
        s_num[wave] = num;
        s_var[wave] = var;
    }
    __syncthreads();
    if (t == 0) {
        float tsl1 = 0.f, tnum = 0.f, tvar = 0.f;
        #pragma unroll
        for (int w = 0; w < 4; ++w) {
            tsl1 += s_sl1[w];
            tnum += s_num[w];
            tvar += s_var[w];
        }
        out[0] = tsl1 / (tnum + 0.0001f) + 0.01f * (tvar / (float)B_);
    }
}

extern "C" void kernel_launch(void* const* d_in, const int* in_sizes, int n_in,
                              void* d_out, int out_size, void* d_ws, size_t ws_size,
                              hipStream_t stream) {
    const float* output = (const float*)d_in[0];  // (256,1,256,256) f32
    const int*   mask   = (const int*)  d_in[1];  // (256,16) i32
    const int*   ind    = (const int*)  d_in[2];  // (256,16) i32
    const float* target = (const float*)d_in[3];  // (256,16,1) f32
    const float* gt2d   = (const float*)d_in[4];  // (256,32) f32
    float*  out     = (float*)d_out;              // scalar f32
    float4* partial = (float4*)d_ws;              // 256 * 16 B = 4 KiB

    fusion_partial<<<B_, 64, 0, stream>>>(output, mask, ind, target, gt2d, partial);
    fusion_final<<<1, 256, 0, stream>>>(partial, out);
}